// Round 3
// baseline (388.887 us; speedup 1.0000x reference)
//
#include <hip/hip_runtime.h>
#include <hip/hip_bf16.h>
#include <cstdint>

// ---------------------------------------------------------------------------
// SAGE GNN, 2 layers, N=50000, E=800000, D: 128 -> 256 -> 128.
//   CSR build: deg histogram -> hierarchical scan -> BINNED two-phase scatter
//   A1[:,128:256] = bf16(x); A1[:,0:128] = mean_in(bf16 x)
//   h   = relu(A1 @ [[W1_l],[W1_r]] + b1)      bf16 MFMA GEMM, K=256,N=256
//   hw2 = h @ [W2_l | W2_r]                    bf16 MFMA GEMM
//   out = mean_in(hw2[:,:128]) + hw2[:,128:] + b2
// ---------------------------------------------------------------------------

static inline size_t align_up(size_t x, size_t a) { return (x + a - 1) & ~(a - 1); }

using short8 = __attribute__((ext_vector_type(8))) short;
using f32x4  = __attribute__((ext_vector_type(4))) float;

#define BSHIFT 6   // bucket = dst >> 6 ; 64 nodes per bucket

__device__ __forceinline__ float bfpair_lo(unsigned int v) {
  union { unsigned int i; float f; } u; u.i = v << 16; return u.f;
}
__device__ __forceinline__ float bfpair_hi(unsigned int v) {
  union { unsigned int i; float f; } u; u.i = v & 0xffff0000u; return u.f;
}
__device__ __forceinline__ unsigned short f2bf(float f) {
  union { float f; unsigned int i; } u; u.f = f;
  unsigned int r = u.i + 0x7fffu + ((u.i >> 16) & 1u);
  return (unsigned short)(r >> 16);
}

__device__ __forceinline__ void gload_lds16(const void* g, void* l) {
  __builtin_amdgcn_global_load_lds(
      (const __attribute__((address_space(1))) void*)g,
      (__attribute__((address_space(3))) void*)l, 16, 0, 0);
}

// ------------------------------- CSR build ---------------------------------

__global__ void count_deg_kernel(const int* __restrict__ dst, int* __restrict__ deg, int E) {
  int e = blockIdx.x * blockDim.x + threadIdx.x;
  if (e < E) atomicAdd(&deg[dst[e]], 1);
}

// per-1024-segment sums (256 threads x int4)
__global__ void scan_part1(const int* __restrict__ deg, int* __restrict__ bsum, int n) {
  int b = blockIdx.x, t = threadIdx.x;
  int base = b * 1024 + t * 4;
  int4 v = make_int4(0, 0, 0, 0);
  if (base < n) v = *reinterpret_cast<const int4*>(deg + base);
  int s = v.x + v.y + v.z + v.w;
  #pragma unroll
  for (int off = 1; off < 64; off <<= 1) s += __shfl_xor(s, off, 64);
  __shared__ int ws_[4];
  if ((t & 63) == 0) ws_[t >> 6] = s;
  __syncthreads();
  if (t == 0) bsum[b] = ws_[0] + ws_[1] + ws_[2] + ws_[3];
}

// single wave: exclusive-scan nb (<=64) block sums in place; rowptr[n] = total
__global__ void scan_part2(int* __restrict__ bsum, int* __restrict__ rowptr, int nb, int n) {
  int t = threadIdx.x;  // 64
  int v = (t < nb) ? bsum[t] : 0;
  int inc = v;
  #pragma unroll
  for (int off = 1; off < 64; off <<= 1) {
    int u = __shfl_up(inc, off, 64);
    if (t >= off) inc += u;
  }
  if (t < nb) bsum[t] = inc - v;
  if (t == 63) rowptr[n] = inc;
}

// per-segment exclusive scan + segment offset -> rowptr
__global__ void scan_part3(const int* __restrict__ deg, const int* __restrict__ bsum,
                           int* __restrict__ rowptr, int n) {
  int b = blockIdx.x, t = threadIdx.x;  // 256
  int base = b * 1024 + t * 4;
  int4 v = make_int4(0, 0, 0, 0);
  if (base < n) v = *reinterpret_cast<const int4*>(deg + base);
  int tsum = v.x + v.y + v.z + v.w;
  int lane = t & 63, w = t >> 6;
  int inc = tsum;
  #pragma unroll
  for (int off = 1; off < 64; off <<= 1) {
    int u = __shfl_up(inc, off, 64);
    if (lane >= off) inc += u;
  }
  __shared__ int wsum[4];
  if (lane == 63) wsum[w] = inc;
  __syncthreads();
  int woff = bsum[b];
  for (int i = 0; i < w; ++i) woff += wsum[i];
  if (base < n) {
    int e0 = woff + inc - tsum;
    int4 r;
    r.x = e0;
    r.y = e0 + v.x;
    r.z = e0 + v.x + v.y;
    r.w = e0 + v.x + v.y + v.z;
    *reinterpret_cast<int4*>(rowptr + base) = r;
  }
}

// bcur[b] = rowptr[b<<BSHIFT]
__global__ void init_bcur_kernel(const int* __restrict__ rowptr, int* __restrict__ bcur, int NB) {
  int b = blockIdx.x * blockDim.x + threadIdx.x;
  if (b < NB) bcur[b] = rowptr[b << BSHIFT];
}

// phase 1: bin edges by dst bucket; sequential 8B writes within bucket region
__global__ void bin_kernel(const int* __restrict__ src, const int* __restrict__ dst,
                           int* __restrict__ bcur, uint2* __restrict__ stage, int E) {
  int e = blockIdx.x * blockDim.x + threadIdx.x;
  if (e < E) {
    int d = dst[e];
    int p = atomicAdd(&bcur[d >> BSHIFT], 1);
    stage[p] = make_uint2((unsigned)src[e], (unsigned)d);
  }
}

// phase 2: one block per bucket; writes confined to ~4KB col region
__global__ __launch_bounds__(256) void scatter2_kernel(const uint2* __restrict__ stage,
                                                       const int* __restrict__ rowptr,
                                                       int* __restrict__ cursor,
                                                       int* __restrict__ col, int N) {
  int b = blockIdx.x;
  int n0 = b << BSHIFT;
  int n1 = n0 + (1 << BSHIFT); if (n1 > N) n1 = N;
  int lo = rowptr[n0], hi = rowptr[n1];
  for (int e = lo + threadIdx.x; e < hi; e += 256) {
    uint2 pr = stage[e];
    int d = (int)pr.y;
    int p = atomicAdd(&cursor[d], 1);
    col[rowptr[d] + p] = (int)pr.x;
  }
}

// ------------------------- weight prep (bf16, transposed) ------------------
// grid 512: blocks 0..255 -> BT1, 256..511 -> BT2
// BT1[n][k]: k<128 -> W1_l[k][n] ; k>=128 -> W1_r[k-128][n]
// BT2[n][k]: n<128 -> W2_l[k][n] ; n>=128 -> W2_r[k][n-128]
__global__ void build_bt_kernel(const float* __restrict__ W1l, const float* __restrict__ W1r,
                                const float* __restrict__ W2l, const float* __restrict__ W2r,
                                __hip_bfloat16* __restrict__ BT1,
                                __hip_bfloat16* __restrict__ BT2) {
  int bb = blockIdx.x;
  int idx = (bb & 255) * 256 + threadIdx.x;
  int n = idx >> 8, k = idx & 255;
  if (bb < 256) {
    float v = (k < 128) ? W1l[k * 256 + n] : W1r[(k - 128) * 256 + n];
    BT1[idx] = __float2bfloat16(v);
  } else {
    float v = (n < 128) ? W2l[k * 128 + n] : W2r[k * 128 + (n - 128)];
    BT2[idx] = __float2bfloat16(v);
  }
}

// A1[i][128+j] = bf16(x[i][j]); thread handles 4 consecutive j
__global__ void convert_x_kernel(const float* __restrict__ x, __hip_bfloat16* __restrict__ A1,
                                 int total4) {
  int idx = blockIdx.x * blockDim.x + threadIdx.x;
  if (idx >= total4) return;
  int i = idx >> 5, j4 = (idx & 31) << 2;
  float4 v = *reinterpret_cast<const float4*>(x + (size_t)i * 128 + j4);
  unsigned int p0 = ((unsigned)f2bf(v.y) << 16) | f2bf(v.x);
  unsigned int p1 = ((unsigned)f2bf(v.w) << 16) | f2bf(v.z);
  uint2 pk = make_uint2(p0, p1);
  *reinterpret_cast<uint2*>(A1 + (size_t)i * 256 + 128 + j4) = pk;
}

// ------------------------------ aggregations -------------------------------

// A1[i][0:128] = mean over in-neighbors of A1[s][128:256]  (bf16 in/out, fp32 acc)
__global__ __launch_bounds__(64) void agg1_kernel(const int* __restrict__ rowptr,
                                                  const int* __restrict__ col,
                                                  __hip_bfloat16* __restrict__ A1) {
  const int i = blockIdx.x;
  const int t = threadIdx.x;  // 0..63
  const int beg = rowptr[i], end = rowptr[i + 1];
  float ax = 0.f, ay = 0.f;
  int e = beg;
  for (; e + 1 < end; e += 2) {
    int s0 = col[e], s1 = col[e + 1];
    unsigned int v0 = *reinterpret_cast<const unsigned int*>(A1 + (size_t)s0 * 256 + 128 + t * 2);
    unsigned int v1 = *reinterpret_cast<const unsigned int*>(A1 + (size_t)s1 * 256 + 128 + t * 2);
    ax += bfpair_lo(v0) + bfpair_lo(v1);
    ay += bfpair_hi(v0) + bfpair_hi(v1);
  }
  if (e < end) {
    int s0 = col[e];
    unsigned int v0 = *reinterpret_cast<const unsigned int*>(A1 + (size_t)s0 * 256 + 128 + t * 2);
    ax += bfpair_lo(v0);
    ay += bfpair_hi(v0);
  }
  int d = end - beg;
  float inv = 1.0f / (float)(d > 1 ? d : 1);
  unsigned int pk = ((unsigned)f2bf(ay * inv) << 16) | f2bf(ax * inv);
  *reinterpret_cast<unsigned int*>(A1 + (size_t)i * 256 + t * 2) = pk;
}

// out[i] = mean_in(hw2[:,:128]) + hw2[i,128:] + b2   (fp32 out)
__global__ __launch_bounds__(64) void agg2_kernel(const __hip_bfloat16* __restrict__ hw2,
                                                  const int* __restrict__ rowptr,
                                                  const int* __restrict__ col,
                                                  const float* __restrict__ b2,
                                                  float* __restrict__ out) {
  const int i = blockIdx.x;
  const int t = threadIdx.x;  // 0..63
  const int beg = rowptr[i], end = rowptr[i + 1];
  float ax = 0.f, ay = 0.f;
  int e = beg;
  for (; e + 1 < end; e += 2) {
    int s0 = col[e], s1 = col[e + 1];
    unsigned int v0 = *reinterpret_cast<const unsigned int*>(hw2 + (size_t)s0 * 256 + t * 2);
    unsigned int v1 = *reinterpret_cast<const unsigned int*>(hw2 + (size_t)s1 * 256 + t * 2);
    ax += bfpair_lo(v0) + bfpair_lo(v1);
    ay += bfpair_hi(v0) + bfpair_hi(v1);
  }
  if (e < end) {
    int s0 = col[e];
    unsigned int v0 = *reinterpret_cast<const unsigned int*>(hw2 + (size_t)s0 * 256 + t * 2);
    ax += bfpair_lo(v0);
    ay += bfpair_hi(v0);
  }
  int d = end - beg;
  float inv = 1.0f / (float)(d > 1 ? d : 1);
  unsigned int sv = *reinterpret_cast<const unsigned int*>(hw2 + (size_t)i * 256 + 128 + t * 2);
  float2 bb = *reinterpret_cast<const float2*>(b2 + t * 2);
  float2 r;
  r.x = ax * inv + bfpair_lo(sv) + bb.x;
  r.y = ay * inv + bfpair_hi(sv) + bb.y;
  *reinterpret_cast<float2*>(out + (size_t)i * 128 + t * 2) = r;
}

// ------------------------------ MFMA GEMM ----------------------------------
// C[M,256] = A[M,256] @ B[256,256] (+bias, relu), all bf16, fp32 accum.
// BT is B transposed: BT[n][k]. Tile 128x128, BK=32, 256 thr (4 waves, 2x2),
// per-wave 64x64 = 4x4 fragments of 16x16x32. global_load_lds width 16.
template <bool BIAS_RELU>
__global__ __launch_bounds__(256) void mfma_gemm_kernel(
    const __hip_bfloat16* __restrict__ A,   // [M][256]
    const __hip_bfloat16* __restrict__ BT,  // [256][256]
    const float* __restrict__ bias,         // [256] or null
    __hip_bfloat16* __restrict__ C,         // [M][256]
    int M) {
  __shared__ __hip_bfloat16 As[128 * 32];
  __shared__ __hip_bfloat16 Bs[128 * 32];
  const int t = threadIdx.x;
  const int lane = t & 63;
  const int w = t >> 6;
  const int bm = blockIdx.x * 128;
  const int bn = blockIdx.y * 128;
  const int wr = (w >> 1) * 64;
  const int wc = (w & 1) * 64;

  const int srow = lane >> 2;
  const int sbyte = (lane & 3) * 16;

  f32x4 acc[4][4];
  #pragma unroll
  for (int i = 0; i < 4; ++i)
    #pragma unroll
    for (int j = 0; j < 4; ++j) acc[i][j] = (f32x4)(0.f);

  const int frow_a = wr + (lane & 15);
  const int frow_b = wc + (lane & 15);
  const int fbyte = (lane >> 4) * 16;

  for (int k0 = 0; k0 < 256; k0 += 32) {
    #pragma unroll
    for (int q = 0; q < 2; ++q) {
      const int chunk = w * 2 + q;
      const int row = chunk * 16 + srow;
      int gr = bm + row;
      if (gr >= M) gr = M - 1;
      gload_lds16((const char*)A + (size_t)gr * 512 + k0 * 2 + sbyte,
                  (char*)As + chunk * 1024);
      gload_lds16((const char*)BT + (size_t)(bn + row) * 512 + k0 * 2 + sbyte,
                  (char*)Bs + chunk * 1024);
    }
    __syncthreads();
    short8 af[4], bf[4];
    #pragma unroll
    for (int i = 0; i < 4; ++i) {
      af[i] = *reinterpret_cast<const short8*>((const char*)As + (frow_a + i * 16) * 64 + fbyte);
      bf[i] = *reinterpret_cast<const short8*>((const char*)Bs + (frow_b + i * 16) * 64 + fbyte);
    }
    #pragma unroll
    for (int i = 0; i < 4; ++i)
      #pragma unroll
      for (int j = 0; j < 4; ++j)
        acc[i][j] = __builtin_amdgcn_mfma_f32_16x16x32_bf16(af[i], bf[j], acc[i][j], 0, 0, 0);
    __syncthreads();
  }

  const int crow0 = bm + wr + (lane >> 4) * 4;
  const int ccol0 = bn + wc + (lane & 15);
  float bj[4] = {0.f, 0.f, 0.f, 0.f};
  if (BIAS_RELU) {
    #pragma unroll
    for (int j = 0; j < 4; ++j) bj[j] = bias[ccol0 + j * 16];
  }
  #pragma unroll
  for (int i = 0; i < 4; ++i) {
    #pragma unroll
    for (int q = 0; q < 4; ++q) {
      const int r = crow0 + i * 16 + q;
      if (r < M) {
        #pragma unroll
        for (int j = 0; j < 4; ++j) {
          float v = acc[i][j][q];
          if (BIAS_RELU) v = fmaxf(v + bj[j], 0.f);
          C[(size_t)r * 256 + ccol0 + j * 16] = __float2bfloat16(v);
        }
      }
    }
  }
}

// ------------------------------ launcher -----------------------------------

extern "C" void kernel_launch(void* const* d_in, const int* in_sizes, int n_in,
                              void* d_out, int out_size, void* d_ws, size_t ws_size,
                              hipStream_t stream) {
  const float* x    = (const float*)d_in[0];
  const int*   edge = (const int*)d_in[1];
  const float* W1_l = (const float*)d_in[2];
  const float* b1   = (const float*)d_in[3];
  const float* W1_r = (const float*)d_in[4];
  const float* W2_l = (const float*)d_in[5];
  const float* b2   = (const float*)d_in[6];
  const float* W2_r = (const float*)d_in[7];
  float* out = (float*)d_out;

  const int N = in_sizes[0] / 128;
  const int E = in_sizes[1] / 2;
  const int* srcv = edge;
  const int* dstv = edge + E;
  const int NB = (N + (1 << BSHIFT) - 1) >> BSHIFT;

  char* ws = (char*)d_ws;
  size_t off = 0;
  auto alloc = [&](size_t bytes) -> void* {
    void* p = ws + off;
    off += align_up(bytes, 256);
    return p;
  };
  int* deg    = (int*)alloc((size_t)N * 4);
  int* cursor = (int*)alloc((size_t)N * 4);
  int* rowptr = (int*)alloc((size_t)(N + 1) * 4);
  int* bsum   = (int*)alloc(64 * 4);
  int* bcur   = (int*)alloc((size_t)NB * 4);
  int* col    = (int*)alloc((size_t)E * 4);
  uint2* stage = (uint2*)alloc((size_t)E * 8);
  __hip_bfloat16* BT1 = (__hip_bfloat16*)alloc(256 * 256 * 2);
  __hip_bfloat16* BT2 = (__hip_bfloat16*)alloc(256 * 256 * 2);
  __hip_bfloat16* A1  = (__hip_bfloat16*)alloc((size_t)N * 256 * 2);
  __hip_bfloat16* h   = (__hip_bfloat16*)alloc((size_t)N * 256 * 2);
  __hip_bfloat16* hw2 = (__hip_bfloat16*)alloc((size_t)N * 256 * 2);

  hipMemsetAsync(deg, 0, (size_t)N * 4, stream);
  hipMemsetAsync(cursor, 0, (size_t)N * 4, stream);

  build_bt_kernel<<<512, 256, 0, stream>>>(W1_l, W1_r, W2_l, W2_r, BT1, BT2);
  convert_x_kernel<<<(N * 32 + 255) / 256, 256, 0, stream>>>(x, A1, N * 32);

  const int eb = (E + 255) / 256;
  count_deg_kernel<<<eb, 256, 0, stream>>>(dstv, deg, E);
  const int nb = (N + 1023) / 1024;  // 49 (<=64 required by scan_part2)
  scan_part1<<<nb, 256, 0, stream>>>(deg, bsum, N);
  scan_part2<<<1, 64, 0, stream>>>(bsum, rowptr, nb, N);
  scan_part3<<<nb, 256, 0, stream>>>(deg, bsum, rowptr, N);

  init_bcur_kernel<<<(NB + 255) / 256, 256, 0, stream>>>(rowptr, bcur, NB);
  bin_kernel<<<eb, 256, 0, stream>>>(srcv, dstv, bcur, stage, E);
  scatter2_kernel<<<NB, 256, 0, stream>>>(stage, rowptr, cursor, col, N);

  agg1_kernel<<<N, 64, 0, stream>>>(rowptr, col, A1);

  dim3 gemm_grid((N + 127) / 128, 2);
  mfma_gemm_kernel<true><<<gemm_grid, 256, 0, stream>>>(A1, BT1, b1, h, N);
  mfma_gemm_kernel<false><<<gemm_grid, 256, 0, stream>>>(h, BT2, nullptr, hw2, N);

  agg2_kernel<<<N, 64, 0, stream>>>(hw2, rowptr, col, b2, out);
}

// Round 4
// 170.399 us; speedup vs baseline: 2.2822x; 2.2822x over previous
//
#include <hip/hip_runtime.h>
#include <hip/hip_bf16.h>
#include <cstdint>

// ---------------------------------------------------------------------------
// SAGE GNN, 2 layers, N=50000, E=800000, D: 128 -> 256 -> 128.
// CSR build via contention-free two-level counting sort:
//   bhist: per-block LDS hist over 782 dst-buckets -> global bucket hist
//   bscan: scan bucket hist -> brow/bcur
//   bin2:  per-block LDS hist + ONE returning atomic per (block,bucket)
//          chunk reservation -> bucket-sorted stage[] of (src,dst)
//   scatter2b: block per bucket; per-node deg + scan in LDS -> rowptr, col
// Then:
//   A1[:,128:256] = bf16(x); A1[:,0:128] = mean_in(bf16 x)
//   h   = relu(A1 @ [[W1_l],[W1_r]] + b1)   bf16 MFMA GEMM, K=256,N=256
//   hw2 = h @ [W2_l | W2_r]                 bf16 MFMA GEMM
//   out = mean_in(hw2[:,:128]) + hw2[:,128:] + b2
// ---------------------------------------------------------------------------

static inline size_t align_up(size_t x, size_t a) { return (x + a - 1) & ~(a - 1); }

using short8 = __attribute__((ext_vector_type(8))) short;
using f32x4  = __attribute__((ext_vector_type(4))) float;

#define BSHIFT 6  // 64 nodes per bucket; NB = ceil(N/64) = 782 (must be <= 1024)

__device__ __forceinline__ float bfpair_lo(unsigned int v) {
  union { unsigned int i; float f; } u; u.i = v << 16; return u.f;
}
__device__ __forceinline__ float bfpair_hi(unsigned int v) {
  union { unsigned int i; float f; } u; u.i = v & 0xffff0000u; return u.f;
}
__device__ __forceinline__ unsigned short f2bf(float f) {
  union { float f; unsigned int i; } u; u.f = f;
  unsigned int r = u.i + 0x7fffu + ((u.i >> 16) & 1u);
  return (unsigned short)(r >> 16);
}

__device__ __forceinline__ void gload_lds16(const void* g, void* l) {
  __builtin_amdgcn_global_load_lds(
      (const __attribute__((address_space(1))) void*)g,
      (__attribute__((address_space(3))) void*)l, 16, 0, 0);
}

// ------------------------------- CSR build ---------------------------------

// per-block LDS bucket histogram -> one no-return global add per (block,bucket)
__global__ __launch_bounds__(256) void bhist_kernel(const int* __restrict__ dst,
                                                    int* __restrict__ bhist,
                                                    int E, int NB, int chunk) {
  __shared__ int h[1024];
  const int t = threadIdx.x;
  for (int i = t; i < NB; i += 256) h[i] = 0;
  __syncthreads();
  const int e0 = blockIdx.x * chunk;
  int e1 = e0 + chunk; if (e1 > E) e1 = E;
  for (int e = e0 + t; e < e1; e += 256) atomicAdd(&h[dst[e] >> BSHIFT], 1);
  __syncthreads();
  for (int i = t; i < NB; i += 256)
    if (h[i]) atomicAdd(&bhist[i], h[i]);
}

// one block, 256 threads x int4: exclusive scan of bhist[0..NB) (zero-padded
// to 1024) -> brow[0..NB], bcur[0..NB)
__global__ __launch_bounds__(256) void bscan_kernel(const int* __restrict__ bhist,
                                                    int* __restrict__ brow,
                                                    int* __restrict__ bcur, int NB) {
  const int t = threadIdx.x;
  int4 v = *reinterpret_cast<const int4*>(bhist + t * 4);
  int tsum = v.x + v.y + v.z + v.w;
  const int lane = t & 63, w = t >> 6;
  int inc = tsum;
  #pragma unroll
  for (int off = 1; off < 64; off <<= 1) {
    int u = __shfl_up(inc, off, 64);
    if (lane >= off) inc += u;
  }
  __shared__ int wsum[4];
  if (lane == 63) wsum[w] = inc;
  __syncthreads();
  int woff = 0;
  for (int i = 0; i < w; ++i) woff += wsum[i];
  int e0 = woff + inc - tsum;
  const int base = t * 4;
  int p[4];
  p[0] = e0;
  p[1] = e0 + v.x;
  p[2] = p[1] + v.y;
  p[3] = p[2] + v.z;
  #pragma unroll
  for (int j = 0; j < 4; ++j) {
    if (base + j < NB) { brow[base + j] = p[j]; bcur[base + j] = p[j]; }
  }
  if (t == 0) brow[NB] = wsum[0] + wsum[1] + wsum[2] + wsum[3];
}

// per-block: LDS hist, chunk reservation (1 returning atomic per bucket per
// block), then place pairs at LDS-cursor positions -> bucket-sorted stage
__global__ __launch_bounds__(256) void bin2_kernel(const int* __restrict__ src,
                                                   const int* __restrict__ dst,
                                                   int* __restrict__ bcur,
                                                   uint2* __restrict__ stage,
                                                   int E, int NB, int chunk) {
  __shared__ int hist[1024];
  __shared__ int base[1024];
  const int t = threadIdx.x;
  const int e0 = blockIdx.x * chunk;
  int e1 = e0 + chunk; if (e1 > E) e1 = E;
  for (int i = t; i < NB; i += 256) hist[i] = 0;
  __syncthreads();
  for (int e = e0 + t; e < e1; e += 256) atomicAdd(&hist[dst[e] >> BSHIFT], 1);
  __syncthreads();
  for (int i = t; i < NB; i += 256) {
    int c = hist[i];
    base[i] = c ? atomicAdd(&bcur[i], c) : 0;
    hist[i] = 0;  // reuse as cursor
  }
  __syncthreads();
  for (int e = e0 + t; e < e1; e += 256) {
    int d = dst[e];
    int b = d >> BSHIFT;
    int p = atomicAdd(&hist[b], 1);
    stage[base[b] + p] = make_uint2((unsigned)src[e], (unsigned)d);
  }
}

// one block per bucket: node-local deg count + scan in LDS -> rowptr, col
__global__ __launch_bounds__(256) void scatter2b_kernel(const uint2* __restrict__ stage,
                                                        const int* __restrict__ brow,
                                                        int* __restrict__ rowptr,
                                                        int* __restrict__ col,
                                                        int N, int E) {
  __shared__ int dcnt[64];
  __shared__ int dbase[64];
  const int b = blockIdx.x;
  const int t = threadIdx.x;
  const int n0 = b << BSHIFT;
  const int lo = brow[b], hi = brow[b + 1];
  if (t < 64) dcnt[t] = 0;
  __syncthreads();
  for (int e = lo + t; e < hi; e += 256) atomicAdd(&dcnt[stage[e].y & 63], 1);
  __syncthreads();
  if (t < 64) {
    int v = dcnt[t];
    int inc = v;
    #pragma unroll
    for (int off = 1; off < 64; off <<= 1) {
      int u = __shfl_up(inc, off, 64);
      if (t >= off) inc += u;
    }
    int excl = lo + inc - v;
    dbase[t] = excl;
    dcnt[t] = 0;  // reuse as cursor
    if (n0 + t < N) rowptr[n0 + t] = excl;
  }
  if (b == 0 && t == 0) rowptr[N] = E;
  __syncthreads();
  for (int e = lo + t; e < hi; e += 256) {
    uint2 pr = stage[e];
    int d = (int)pr.y & 63;
    int p = atomicAdd(&dcnt[d], 1);
    col[dbase[d] + p] = (int)pr.x;
  }
}

// ------------------------- weight prep (bf16, transposed) ------------------
// grid 512: blocks 0..255 -> BT1, 256..511 -> BT2
// BT1[n][k]: k<128 -> W1_l[k][n] ; k>=128 -> W1_r[k-128][n]
// BT2[n][k]: n<128 -> W2_l[k][n] ; n>=128 -> W2_r[k][n-128]
__global__ void build_bt_kernel(const float* __restrict__ W1l, const float* __restrict__ W1r,
                                const float* __restrict__ W2l, const float* __restrict__ W2r,
                                __hip_bfloat16* __restrict__ BT1,
                                __hip_bfloat16* __restrict__ BT2) {
  int bb = blockIdx.x;
  int idx = (bb & 255) * 256 + threadIdx.x;
  int n = idx >> 8, k = idx & 255;
  if (bb < 256) {
    float v = (k < 128) ? W1l[k * 256 + n] : W1r[(k - 128) * 256 + n];
    BT1[idx] = __float2bfloat16(v);
  } else {
    float v = (n < 128) ? W2l[k * 128 + n] : W2r[k * 128 + (n - 128)];
    BT2[idx] = __float2bfloat16(v);
  }
}

// A1[i][128+j] = bf16(x[i][j]); thread handles 4 consecutive j
__global__ void convert_x_kernel(const float* __restrict__ x, __hip_bfloat16* __restrict__ A1,
                                 int total4) {
  int idx = blockIdx.x * blockDim.x + threadIdx.x;
  if (idx >= total4) return;
  int i = idx >> 5, j4 = (idx & 31) << 2;
  float4 v = *reinterpret_cast<const float4*>(x + (size_t)i * 128 + j4);
  unsigned int p0 = ((unsigned)f2bf(v.y) << 16) | f2bf(v.x);
  unsigned int p1 = ((unsigned)f2bf(v.w) << 16) | f2bf(v.z);
  uint2 pk = make_uint2(p0, p1);
  *reinterpret_cast<uint2*>(A1 + (size_t)i * 256 + 128 + j4) = pk;
}

// ------------------------------ aggregations -------------------------------

// A1[i][0:128] = mean over in-neighbors of A1[s][128:256]  (bf16 in/out, fp32 acc)
__global__ __launch_bounds__(64) void agg1_kernel(const int* __restrict__ rowptr,
                                                  const int* __restrict__ col,
                                                  __hip_bfloat16* __restrict__ A1) {
  const int i = blockIdx.x;
  const int t = threadIdx.x;  // 0..63
  const int beg = rowptr[i], end = rowptr[i + 1];
  float ax = 0.f, ay = 0.f;
  int e = beg;
  for (; e + 1 < end; e += 2) {
    int s0 = col[e], s1 = col[e + 1];
    unsigned int v0 = *reinterpret_cast<const unsigned int*>(A1 + (size_t)s0 * 256 + 128 + t * 2);
    unsigned int v1 = *reinterpret_cast<const unsigned int*>(A1 + (size_t)s1 * 256 + 128 + t * 2);
    ax += bfpair_lo(v0) + bfpair_lo(v1);
    ay += bfpair_hi(v0) + bfpair_hi(v1);
  }
  if (e < end) {
    int s0 = col[e];
    unsigned int v0 = *reinterpret_cast<const unsigned int*>(A1 + (size_t)s0 * 256 + 128 + t * 2);
    ax += bfpair_lo(v0);
    ay += bfpair_hi(v0);
  }
  int d = end - beg;
  float inv = 1.0f / (float)(d > 1 ? d : 1);
  unsigned int pk = ((unsigned)f2bf(ay * inv) << 16) | f2bf(ax * inv);
  *reinterpret_cast<unsigned int*>(A1 + (size_t)i * 256 + t * 2) = pk;
}

// out[i] = mean_in(hw2[:,:128]) + hw2[i,128:] + b2   (fp32 out)
__global__ __launch_bounds__(64) void agg2_kernel(const __hip_bfloat16* __restrict__ hw2,
                                                  const int* __restrict__ rowptr,
                                                  const int* __restrict__ col,
                                                  const float* __restrict__ b2,
                                                  float* __restrict__ out) {
  const int i = blockIdx.x;
  const int t = threadIdx.x;  // 0..63
  const int beg = rowptr[i], end = rowptr[i + 1];
  float ax = 0.f, ay = 0.f;
  int e = beg;
  for (; e + 1 < end; e += 2) {
    int s0 = col[e], s1 = col[e + 1];
    unsigned int v0 = *reinterpret_cast<const unsigned int*>(hw2 + (size_t)s0 * 256 + t * 2);
    unsigned int v1 = *reinterpret_cast<const unsigned int*>(hw2 + (size_t)s1 * 256 + t * 2);
    ax += bfpair_lo(v0) + bfpair_lo(v1);
    ay += bfpair_hi(v0) + bfpair_hi(v1);
  }
  if (e < end) {
    int s0 = col[e];
    unsigned int v0 = *reinterpret_cast<const unsigned int*>(hw2 + (size_t)s0 * 256 + t * 2);
    ax += bfpair_lo(v0);
    ay += bfpair_hi(v0);
  }
  int d = end - beg;
  float inv = 1.0f / (float)(d > 1 ? d : 1);
  unsigned int sv = *reinterpret_cast<const unsigned int*>(hw2 + (size_t)i * 256 + 128 + t * 2);
  float2 bb = *reinterpret_cast<const float2*>(b2 + t * 2);
  float2 r;
  r.x = ax * inv + bfpair_lo(sv) + bb.x;
  r.y = ay * inv + bfpair_hi(sv) + bb.y;
  *reinterpret_cast<float2*>(out + (size_t)i * 128 + t * 2) = r;
}

// ------------------------------ MFMA GEMM ----------------------------------
// C[M,256] = A[M,256] @ B[256,256] (+bias, relu), all bf16, fp32 accum.
// BT is B transposed: BT[n][k]. Tile 128x128, BK=32, 256 thr (4 waves, 2x2),
// per-wave 64x64 = 4x4 fragments of 16x16x32. global_load_lds width 16.
template <bool BIAS_RELU>
__global__ __launch_bounds__(256) void mfma_gemm_kernel(
    const __hip_bfloat16* __restrict__ A,   // [M][256]
    const __hip_bfloat16* __restrict__ BT,  // [256][256]
    const float* __restrict__ bias,         // [256] or null
    __hip_bfloat16* __restrict__ C,         // [M][256]
    int M) {
  __shared__ __hip_bfloat16 As[128 * 32];
  __shared__ __hip_bfloat16 Bs[128 * 32];
  const int t = threadIdx.x;
  const int lane = t & 63;
  const int w = t >> 6;
  const int bm = blockIdx.x * 128;
  const int bn = blockIdx.y * 128;
  const int wr = (w >> 1) * 64;
  const int wc = (w & 1) * 64;

  const int srow = lane >> 2;
  const int sbyte = (lane & 3) * 16;

  f32x4 acc[4][4];
  #pragma unroll
  for (int i = 0; i < 4; ++i)
    #pragma unroll
    for (int j = 0; j < 4; ++j) acc[i][j] = (f32x4)(0.f);

  const int frow_a = wr + (lane & 15);
  const int frow_b = wc + (lane & 15);
  const int fbyte = (lane >> 4) * 16;

  for (int k0 = 0; k0 < 256; k0 += 32) {
    #pragma unroll
    for (int q = 0; q < 2; ++q) {
      const int chunk = w * 2 + q;
      const int row = chunk * 16 + srow;
      int gr = bm + row;
      if (gr >= M) gr = M - 1;
      gload_lds16((const char*)A + (size_t)gr * 512 + k0 * 2 + sbyte,
                  (char*)As + chunk * 1024);
      gload_lds16((const char*)BT + (size_t)(bn + row) * 512 + k0 * 2 + sbyte,
                  (char*)Bs + chunk * 1024);
    }
    __syncthreads();
    short8 af[4], bf[4];
    #pragma unroll
    for (int i = 0; i < 4; ++i) {
      af[i] = *reinterpret_cast<const short8*>((const char*)As + (frow_a + i * 16) * 64 + fbyte);
      bf[i] = *reinterpret_cast<const short8*>((const char*)Bs + (frow_b + i * 16) * 64 + fbyte);
    }
    #pragma unroll
    for (int i = 0; i < 4; ++i)
      #pragma unroll
      for (int j = 0; j < 4; ++j)
        acc[i][j] = __builtin_amdgcn_mfma_f32_16x16x32_bf16(af[i], bf[j], acc[i][j], 0, 0, 0);
    __syncthreads();
  }

  const int crow0 = bm + wr + (lane >> 4) * 4;
  const int ccol0 = bn + wc + (lane & 15);
  float bj[4] = {0.f, 0.f, 0.f, 0.f};
  if (BIAS_RELU) {
    #pragma unroll
    for (int j = 0; j < 4; ++j) bj[j] = bias[ccol0 + j * 16];
  }
  #pragma unroll
  for (int i = 0; i < 4; ++i) {
    #pragma unroll
    for (int q = 0; q < 4; ++q) {
      const int r = crow0 + i * 16 + q;
      if (r < M) {
        #pragma unroll
        for (int j = 0; j < 4; ++j) {
          float v = acc[i][j][q];
          if (BIAS_RELU) v = fmaxf(v + bj[j], 0.f);
          C[(size_t)r * 256 + ccol0 + j * 16] = __float2bfloat16(v);
        }
      }
    }
  }
}

// ------------------------------ launcher -----------------------------------

extern "C" void kernel_launch(void* const* d_in, const int* in_sizes, int n_in,
                              void* d_out, int out_size, void* d_ws, size_t ws_size,
                              hipStream_t stream) {
  const float* x    = (const float*)d_in[0];
  const int*   edge = (const int*)d_in[1];
  const float* W1_l = (const float*)d_in[2];
  const float* b1   = (const float*)d_in[3];
  const float* W1_r = (const float*)d_in[4];
  const float* W2_l = (const float*)d_in[5];
  const float* b2   = (const float*)d_in[6];
  const float* W2_r = (const float*)d_in[7];
  float* out = (float*)d_out;

  const int N = in_sizes[0] / 128;
  const int E = in_sizes[1] / 2;
  const int* srcv = edge;
  const int* dstv = edge + E;
  const int NB = (N + (1 << BSHIFT) - 1) >> BSHIFT;  // 782, must be <= 1024

  char* ws = (char*)d_ws;
  size_t off = 0;
  auto alloc = [&](size_t bytes) -> void* {
    void* p = ws + off;
    off += align_up(bytes, 256);
    return p;
  };
  int* rowptr = (int*)alloc((size_t)(N + 1) * 4);
  int* brow   = (int*)alloc((size_t)(NB + 1) * 4);
  int* bcur   = (int*)alloc((size_t)NB * 4);
  int* bhist  = (int*)alloc(1024 * 4);  // zero-padded to 1024 for bscan int4
  int* col    = (int*)alloc((size_t)E * 4);
  uint2* stage = (uint2*)alloc((size_t)E * 8);
  __hip_bfloat16* BT1 = (__hip_bfloat16*)alloc(256 * 256 * 2);
  __hip_bfloat16* BT2 = (__hip_bfloat16*)alloc(256 * 256 * 2);
  __hip_bfloat16* A1  = (__hip_bfloat16*)alloc((size_t)N * 256 * 2);
  __hip_bfloat16* h   = (__hip_bfloat16*)alloc((size_t)N * 256 * 2);
  __hip_bfloat16* hw2 = (__hip_bfloat16*)alloc((size_t)N * 256 * 2);

  hipMemsetAsync(bhist, 0, 1024 * 4, stream);

  build_bt_kernel<<<512, 256, 0, stream>>>(W1_l, W1_r, W2_l, W2_r, BT1, BT2);
  convert_x_kernel<<<(N * 32 + 255) / 256, 256, 0, stream>>>(x, A1, N * 32);

  const int PB = 98;
  const int chunk = (E + PB - 1) / PB;
  bhist_kernel<<<PB, 256, 0, stream>>>(dstv, bhist, E, NB, chunk);
  bscan_kernel<<<1, 256, 0, stream>>>(bhist, brow, bcur, NB);
  bin2_kernel<<<PB, 256, 0, stream>>>(srcv, dstv, bcur, stage, E, NB, chunk);
  scatter2b_kernel<<<NB, 256, 0, stream>>>(stage, brow, rowptr, col, N, E);

  agg1_kernel<<<N, 64, 0, stream>>>(rowptr, col, A1);

  dim3 gemm_grid((N + 127) / 128, 2);
  mfma_gemm_kernel<true><<<gemm_grid, 256, 0, stream>>>(A1, BT1, b1, h, N);
  mfma_gemm_kernel<false><<<gemm_grid, 256, 0, stream>>>(h, BT2, nullptr, hw2, N);

  agg2_kernel<<<N, 64, 0, stream>>>(hw2, rowptr, col, b2, out);
}